// Round 1
// baseline (471.840 us; speedup 1.0000x reference)
//
#include <hip/hip_runtime.h>
#include <math.h>

// Problem constants (match reference)
#define SIGMA_C   1e-4f
#define GAMMA_C   1e-4f
#define ZNEAR_C   1.0f
#define ZFAR_C    100.0f
#define EPSB_C    1e-10f

static constexpr int N_ = 8, H_ = 512, W_ = 512, K_ = 4;
static constexpr int NPIX = N_ * H_ * W_;   // 2,097,152
static constexpr int HW_SHIFT = 18;         // H_*W_ = 2^18

__global__ __launch_bounds__(256) void soft_phong_kernel(
    const float* __restrict__ verts,        // (V,3)
    const float* __restrict__ vnorm,        // (V,3)
    const float* __restrict__ bary,         // (N,H,W,K,3)
    const float* __restrict__ zbuf,         // (N,H,W,K)
    const float* __restrict__ dists,        // (N,H,W,K)
    const float* __restrict__ texels,       // (N,H,W,K,3)
    const float* __restrict__ vis,          // (N,H,W,3)
    const float* __restrict__ l_loc,        // (N,3)
    const float* __restrict__ l_amb,        // (N,3)
    const float* __restrict__ l_dif,        // (N,3)
    const float* __restrict__ l_spec,       // (N,3)
    const float* __restrict__ cam,          // (N,3)
    const float* __restrict__ m_amb,        // (N,3)
    const float* __restrict__ m_dif,        // (N,3)
    const float* __restrict__ m_spec,       // (N,3)
    const float* __restrict__ shininess,    // (N,)
    const int*   __restrict__ faces,        // (F,3)
    const int*   __restrict__ p2f,          // (N,H,W,K)
    float* __restrict__ out)                // (N,H,W,4)
{
    const int p = blockIdx.x * 256 + threadIdx.x;  // flat pixel index, grid sized exactly
    const int n = p >> HW_SHIFT;

    // ---- per-batch uniforms (L1/L2 broadcast; block-uniform n) ----
    const float llx = l_loc[3*n+0], lly = l_loc[3*n+1], llz = l_loc[3*n+2];
    const float ccx = cam[3*n+0],   ccy = cam[3*n+1],   ccz = cam[3*n+2];
    const float ambR = m_amb[3*n+0]*l_amb[3*n+0];
    const float ambG = m_amb[3*n+1]*l_amb[3*n+1];
    const float ambB = m_amb[3*n+2]*l_amb[3*n+2];
    const float kdR  = m_dif[3*n+0]*l_dif[3*n+0];
    const float kdG  = m_dif[3*n+1]*l_dif[3*n+1];
    const float kdB  = m_dif[3*n+2]*l_dif[3*n+2];
    const float ksR  = m_spec[3*n+0]*l_spec[3*n+0];
    const float ksG  = m_spec[3*n+1]*l_spec[3*n+1];
    const float ksB  = m_spec[3*n+2]*l_spec[3*n+2];
    const float shin = shininess[n];

    // ---- streaming per-pixel loads (coalesced, 16B where possible) ----
    const int4   f4 = reinterpret_cast<const int4*>(p2f)[p];
    const float4 z4 = reinterpret_cast<const float4*>(zbuf)[p];
    const float4 d4 = reinterpret_cast<const float4*>(dists)[p];
    const float4 bA = reinterpret_cast<const float4*>(bary)[3*p+0];
    const float4 bB = reinterpret_cast<const float4*>(bary)[3*p+1];
    const float4 bC = reinterpret_cast<const float4*>(bary)[3*p+2];
    const float4 tA = reinterpret_cast<const float4*>(texels)[3*p+0];
    const float4 tB = reinterpret_cast<const float4*>(texels)[3*p+1];
    const float4 tC = reinterpret_cast<const float4*>(texels)[3*p+2];
    const float vR = vis[3*p+0], vG = vis[3*p+1], vB = vis[3*p+2];

    const int   fi[4] = {f4.x, f4.y, f4.z, f4.w};
    const float zb[4] = {z4.x, z4.y, z4.z, z4.w};
    const float dd[4] = {d4.x, d4.y, d4.z, d4.w};
    const float bc[12] = {bA.x,bA.y,bA.z,bA.w, bB.x,bB.y,bB.z,bB.w, bC.x,bC.y,bC.z,bC.w};
    const float tx[12] = {tA.x,tA.y,tA.z,tA.w, tB.x,tB.y,tB.z,tB.w, tC.x,tC.y,tC.z,tC.w};

    float colR[4], colG[4], colB[4], prob[4], zinv[4];
    float zmax = EPSB_C;

#pragma unroll
    for (int k = 0; k < 4; ++k) {
        const int f = fi[k];
        if (f >= 0) {
            // gather face -> 3 vertex indices -> positions + normals (L2-resident)
            const int i0 = faces[3*f+0], i1 = faces[3*f+1], i2 = faces[3*f+2];
            const float b0 = bc[3*k+0], b1 = bc[3*k+1], b2 = bc[3*k+2];

            const float pcx = b0*verts[3*i0+0] + b1*verts[3*i1+0] + b2*verts[3*i2+0];
            const float pcy = b0*verts[3*i0+1] + b1*verts[3*i1+1] + b2*verts[3*i2+1];
            const float pcz = b0*verts[3*i0+2] + b1*verts[3*i1+2] + b2*verts[3*i2+2];

            const float pnx = b0*vnorm[3*i0+0] + b1*vnorm[3*i1+0] + b2*vnorm[3*i2+0];
            const float pny = b0*vnorm[3*i0+1] + b1*vnorm[3*i1+1] + b2*vnorm[3*i2+1];
            const float pnz = b0*vnorm[3*i0+2] + b1*vnorm[3*i1+2] + b2*vnorm[3*i2+2];

            // normals = _normalize(pixel_normals)
            const float nl  = sqrtf(pnx*pnx + pny*pny + pnz*pnz);
            const float inl = 1.0f / fmaxf(nl, 1e-6f);
            const float nx = pnx*inl, ny = pny*inl, nz = pnz*inl;

            // direction = _normalize(light - pc)
            float dx = llx - pcx, dy = lly - pcy, dz = llz - pcz;
            const float dl  = sqrtf(dx*dx + dy*dy + dz*dz);
            const float idl = 1.0f / fmaxf(dl, 1e-6f);
            dx *= idl; dy *= idl; dz *= idl;

            const float cosang = nx*dx + ny*dy + nz*dz;
            const float rcos   = fmaxf(cosang, 0.0f);

            // reflect = -direction + 2*cos*normals
            const float rx = 2.0f*cosang*nx - dx;
            const float ry = 2.0f*cosang*ny - dy;
            const float rz = 2.0f*cosang*nz - dz;

            // view_dir = _normalize(cam - pc)
            float vx = ccx - pcx, vy = ccy - pcy, vz = ccz - pcz;
            const float vl  = sqrtf(vx*vx + vy*vy + vz*vz);
            const float ivl = 1.0f / fmaxf(vl, 1e-6f);
            vx *= ivl; vy *= ivl; vz *= ivl;

            const float sdot = vx*rx + vy*ry + vz*rz;
            const float spec_cos = (cosang > 0.0f) ? fmaxf(sdot, 0.0f) : 0.0f;
            // spec_cos ** shininess (spec_cos in [0,1]); exact 0 for spec_cos==0
            const float sp = (spec_cos > 0.0f) ? exp2f(shin * log2f(spec_cos)) : 0.0f;

            colR[k] = (ambR + kdR*rcos*vR) * tx[3*k+0] + ksR*sp;
            colG[k] = (ambG + kdG*rcos*vG) * tx[3*k+1] + ksG*sp;
            colB[k] = (ambB + kdB*rcos*vB) * tx[3*k+2] + ksB*sp;

            // prob = sigmoid(-d/SIGMA) = 1/(1+exp(d/SIGMA))
            prob[k] = 1.0f / (1.0f + expf(dd[k] / SIGMA_C));
            zinv[k] = (ZFAR_C - zb[k]) / (ZFAR_C - ZNEAR_C);
        } else {
            colR[k] = 0.0f; colG[k] = 0.0f; colB[k] = 0.0f;
            prob[k] = 0.0f; zinv[k] = 0.0f;
        }
        zmax = fmaxf(zmax, zinv[k]);
    }

    // ---- softmax depth blend ----
    const float delta = expf((EPSB_C - zmax) / GAMMA_C);
    float denom = delta;
    float accR = delta, accG = delta, accB = delta;   // delta * BG(1,1,1)
    float keep = 1.0f;                                // prod(1 - prob)
#pragma unroll
    for (int k = 0; k < 4; ++k) {
        const float w = prob[k] * expf((zinv[k] - zmax) / GAMMA_C);
        denom += w;
        accR += w * colR[k];
        accG += w * colG[k];
        accB += w * colB[k];
        keep *= (1.0f - prob[k]);
    }
    const float inv = 1.0f / denom;
    reinterpret_cast<float4*>(out)[p] =
        make_float4(accR*inv, accG*inv, accB*inv, 1.0f - keep);
}

extern "C" void kernel_launch(void* const* d_in, const int* in_sizes, int n_in,
                              void* d_out, int out_size, void* d_ws, size_t ws_size,
                              hipStream_t stream) {
    const float* verts   = (const float*)d_in[0];
    const float* vnorm   = (const float*)d_in[1];
    const float* bary    = (const float*)d_in[2];
    const float* zbuf    = (const float*)d_in[3];
    const float* dists   = (const float*)d_in[4];
    const float* texels  = (const float*)d_in[5];
    const float* vis     = (const float*)d_in[6];
    const float* l_loc   = (const float*)d_in[7];
    const float* l_amb   = (const float*)d_in[8];
    const float* l_dif   = (const float*)d_in[9];
    const float* l_spec  = (const float*)d_in[10];
    const float* cam     = (const float*)d_in[11];
    const float* m_amb   = (const float*)d_in[12];
    const float* m_dif   = (const float*)d_in[13];
    const float* m_spec  = (const float*)d_in[14];
    const float* shin    = (const float*)d_in[15];
    const int*   faces   = (const int*)d_in[16];
    const int*   p2f     = (const int*)d_in[17];
    float* out = (float*)d_out;

    dim3 grid(NPIX / 256), block(256);
    soft_phong_kernel<<<grid, block, 0, stream>>>(
        verts, vnorm, bary, zbuf, dists, texels, vis,
        l_loc, l_amb, l_dif, l_spec, cam,
        m_amb, m_dif, m_spec, shin, faces, p2f, out);
}